// Round 7
// baseline (375.811 us; speedup 1.0000x reference)
//
#include <hip/hip_runtime.h>

#define BB 4
#define NN 256
#define DD 256
#define HH 256

typedef _Float16 half8 __attribute__((ext_vector_type(8)));
typedef __fp16   fp16x2 __attribute__((ext_vector_type(2)));
typedef float floatx4 __attribute__((ext_vector_type(4)));

// ---------- prep: Wc/Wd -> interleaved f16 (chunk-major)  +  S/T projections ----
// Wf16 layout: [c][h][kkloc], c in [0,8), kkloc in [0,64); kk = c*64+kkloc = 2*d+t.
#define RPB 4
__global__ __launch_bounds__(256) void prep_kernel(const float* __restrict__ X,
                                                   const float* __restrict__ W1,
                                                   float* __restrict__ S,
                                                   float* __restrict__ T,
                                                   _Float16* __restrict__ Wf16) {
  const int g = blockIdx.x;    // 0..255
  const int h = threadIdx.x;   // 0..255

  // (a) weight conversion for d = g
  {
    const float wcv = W1[(size_t)(2 * DD + g) * HH + h];
    const float wdv = W1[(size_t)(3 * DD + g) * HH + h];
    const int c  = g >> 5;
    const int dd = g & 31;
    _Float16* p = Wf16 + ((size_t)c * HH * 64 + (size_t)h * 64 + 2 * dd);
    p[0] = (_Float16)wcv;   // RTN
    p[1] = (_Float16)wdv;
  }

  // (b) S/T for 4 rows
  const int row0 = g * RPB;
  __shared__ float xr[RPB][DD];
#pragma unroll
  for (int r = 0; r < RPB; ++r) xr[r][h] = X[(size_t)(row0 + r) * DD + h];
  __syncthreads();
  const float* __restrict__ Wa = W1;
  const float* __restrict__ Wb = W1 + (size_t)DD * HH;
  float sa0 = 0.f, sa1 = 0.f, sa2 = 0.f, sa3 = 0.f;
  float sb0 = 0.f, sb1 = 0.f, sb2 = 0.f, sb3 = 0.f;
  for (int d = 0; d < DD; ++d) {
    const float wa = Wa[(size_t)d * HH + h];
    const float wb = Wb[(size_t)d * HH + h];
    sa0 = fmaf(xr[0][d], wa, sa0);  sb0 = fmaf(xr[0][d], wb, sb0);
    sa1 = fmaf(xr[1][d], wa, sa1);  sb1 = fmaf(xr[1][d], wb, sb1);
    sa2 = fmaf(xr[2][d], wa, sa2);  sb2 = fmaf(xr[2][d], wb, sb2);
    sa3 = fmaf(xr[3][d], wa, sa3);  sb3 = fmaf(xr[3][d], wb, sb3);
  }
  S[(size_t)(row0 + 0) * HH + h] = sa0;  T[(size_t)(row0 + 0) * HH + h] = sb0;
  S[(size_t)(row0 + 1) * HH + h] = sa1;  T[(size_t)(row0 + 1) * HH + h] = sb1;
  S[(size_t)(row0 + 2) * HH + h] = sa2;  T[(size_t)(row0 + 2) * HH + h] = sb2;
  S[(size_t)(row0 + 3) * HH + h] = sa3;  T[(size_t)(row0 + 3) * HH + h] = sb3;
}

// A-fragment: 4 (diff,prod) f16 pairs packed without any stack object.
__device__ __forceinline__ half8 make_afrag(const float4& xi, const float4& xj) {
  fp16x2 p0 = __builtin_amdgcn_cvt_pkrtz(__builtin_fabsf(xi.x - xj.x), xi.x * xj.x);
  fp16x2 p1 = __builtin_amdgcn_cvt_pkrtz(__builtin_fabsf(xi.y - xj.y), xi.y * xj.y);
  fp16x2 p2 = __builtin_amdgcn_cvt_pkrtz(__builtin_fabsf(xi.z - xj.z), xi.z * xj.z);
  fp16x2 p3 = __builtin_amdgcn_cvt_pkrtz(__builtin_fabsf(xi.w - xj.w), xi.w * xj.w);
  uint4 u;
  u.x = __builtin_bit_cast(unsigned int, p0);
  u.y = __builtin_bit_cast(unsigned int, p1);
  u.z = __builtin_bit_cast(unsigned int, p2);
  u.w = __builtin_bit_cast(unsigned int, p3);
  return __builtin_bit_cast(half8, u);
}

#define MFMA16(af, bf, acc) acc = __builtin_amdgcn_mfma_f32_16x16x32_f16(af, bf, acc, 0, 0, 0)

// ---------- kernel 2: MFMA pair-scores + softmax, one block per (b,i) ----------
// 1024 threads = 16 waves; wave (wr=wid&3 -> j-group, wc=wid>>2 -> h-group).
// Each wave: 4 j-tiles x 4 h-tiles, named accumulators (NO local arrays: R4-R6's
// PromoteAlloca moved bpre[]/af-union into LDS/scratch -> 7.3M bank conflicts).
// B frags read directly from L2-resident Wf16 (no LDS staging, no K-loop barriers).
// 82 KB LDS forces 1 block/CU -> compiler targets 4 waves/EU -> 128-reg budget.
__global__
__attribute__((amdgpu_flat_work_group_size(1024, 1024), amdgpu_waves_per_eu(4, 4)))
void score_mfma(
    const float* __restrict__ X,  const float* __restrict__ b1,
    const float* __restrict__ W2, const float* __restrict__ b2,
    const float* __restrict__ S,  const float* __restrict__ T,
    const _Float16* __restrict__ Wf16, float* __restrict__ out) {

  const int bi   = blockIdx.x;
  const int b    = bi >> 8;
  const int i    = bi & 255;
  const int t    = threadIdx.x;
  const int lane = t & 63;
  const int wid  = t >> 6;        // 0..15
  const int wr   = wid & 3;       // j-group
  const int wc   = wid >> 2;      // h-group 0..3
  const int q    = lane >> 4;     // 0..3
  const int cc   = lane & 15;     // 0..15

  __shared__ __align__(16) float xi_s[DD];
  __shared__ float pre_s[HH];
  __shared__ float w2_s[HH];
  __shared__ float sc_s[4 * NN];
  __shared__ float red_s[NN];
  __shared__ float lds_pad[18560];   // 74240 B -> total 82432 B -> 1 block/CU
  if (out == nullptr) lds_pad[t] = 0.f;  // never true; keeps pad allocated

  if (t < 256) {
    xi_s[t]  = X[(size_t)bi * DD + t];
    pre_s[t] = S[(size_t)bi * HH + t] + b1[t];
    w2_s[t]  = W2[t];
  }
  __syncthreads();

  const float* __restrict__ Xb = X + (size_t)b * NN * DD;
  const float* __restrict__ Tb = T + (size_t)b * NN * HH;

  // B-frag element offsets (halves): chunk c at c*16384; row hr at hr*64; +ksl*32+q*8
  const int hroff = ((wc * 4) * 16 + cc) * 64 + q * 8;   // hh advances by +1024
  // A-side X row offsets (floats): row j = (wr*4+jj)*16+cc; jj advances by +16*DD
  const int xoff = ((wr * 4) * 16 + cc) * DD;

  floatx4 a00 = (floatx4)0.f, a01 = (floatx4)0.f, a02 = (floatx4)0.f, a03 = (floatx4)0.f;
  floatx4 a10 = (floatx4)0.f, a11 = (floatx4)0.f, a12 = (floatx4)0.f, a13 = (floatx4)0.f;
  floatx4 a20 = (floatx4)0.f, a21 = (floatx4)0.f, a22 = (floatx4)0.f, a23 = (floatx4)0.f;
  floatx4 a30 = (floatx4)0.f, a31 = (floatx4)0.f, a32 = (floatx4)0.f, a33 = (floatx4)0.f;

#pragma unroll 2
  for (int ks = 0; ks < 16; ++ks) {
    const int cbase = (ks >> 1) * 16384 + (ks & 1) * 32;
    const half8 bf0 = *(const half8*)(Wf16 + cbase + hroff);
    const half8 bf1 = *(const half8*)(Wf16 + cbase + hroff + 1024);
    const half8 bf2 = *(const half8*)(Wf16 + cbase + hroff + 2048);
    const half8 bf3 = *(const half8*)(Wf16 + cbase + hroff + 3072);

    const int dbase = ks * 16 + q * 4;
    const float4 xiv = *(const float4*)&xi_s[dbase];

    {
      const float4 xj = *(const float4*)(Xb + xoff + 0 * 16 * DD + dbase);
      const half8 af = make_afrag(xiv, xj);
      MFMA16(af, bf0, a00); MFMA16(af, bf1, a01); MFMA16(af, bf2, a02); MFMA16(af, bf3, a03);
    }
    {
      const float4 xj = *(const float4*)(Xb + xoff + 1 * 16 * DD + dbase);
      const half8 af = make_afrag(xiv, xj);
      MFMA16(af, bf0, a10); MFMA16(af, bf1, a11); MFMA16(af, bf2, a12); MFMA16(af, bf3, a13);
    }
    {
      const float4 xj = *(const float4*)(Xb + xoff + 2 * 16 * DD + dbase);
      const half8 af = make_afrag(xiv, xj);
      MFMA16(af, bf0, a20); MFMA16(af, bf1, a21); MFMA16(af, bf2, a22); MFMA16(af, bf3, a23);
    }
    {
      const float4 xj = *(const float4*)(Xb + xoff + 3 * 16 * DD + dbase);
      const half8 af = make_afrag(xiv, xj);
      MFMA16(af, bf0, a30); MFMA16(af, bf1, a31); MFMA16(af, bf2, a32); MFMA16(af, bf3, a33);
    }
  }

  // ---- epilogue: add S/T/b1, silu, dot w2 ----
  float p00 = 0.f, p01 = 0.f, p02 = 0.f, p03 = 0.f;
  float p10 = 0.f, p11 = 0.f, p12 = 0.f, p13 = 0.f;
  float p20 = 0.f, p21 = 0.f, p22 = 0.f, p23 = 0.f;
  float p30 = 0.f, p31 = 0.f, p32 = 0.f, p33 = 0.f;

#define EPI_R(ACC, jj, r, P) { \
    const float tv = Tb[(size_t)((wr * 4 + jj) * 16 + q * 4 + r) * HH + h]; \
    const float hv = ACC[r] + pv + tv; \
    const float sv = hv * __frcp_rn(1.f + __expf(-hv)); \
    P = fmaf(sv, w2v, P); }

#define EPI_HH(hh, A0, A1, A2, A3) { \
    const int h = (wc * 4 + hh) * 16 + cc; \
    const float w2v = w2_s[h]; \
    const float pv  = pre_s[h]; \
    EPI_R(A0, 0, 0, p00) EPI_R(A0, 0, 1, p01) EPI_R(A0, 0, 2, p02) EPI_R(A0, 0, 3, p03) \
    EPI_R(A1, 1, 0, p10) EPI_R(A1, 1, 1, p11) EPI_R(A1, 1, 2, p12) EPI_R(A1, 1, 3, p13) \
    EPI_R(A2, 2, 0, p20) EPI_R(A2, 2, 1, p21) EPI_R(A2, 2, 2, p22) EPI_R(A2, 2, 3, p23) \
    EPI_R(A3, 3, 0, p30) EPI_R(A3, 3, 1, p31) EPI_R(A3, 3, 2, p32) EPI_R(A3, 3, 3, p33) }

  EPI_HH(0, a00, a10, a20, a30)
  EPI_HH(1, a01, a11, a21, a31)
  EPI_HH(2, a02, a12, a22, a32)
  EPI_HH(3, a03, a13, a23, a33)

  // reduce over the 16 h-columns (lane bits 0..3), lane cc==0 writes
#define REDW(P, jj, r) { \
    float v = P; \
    v += __shfl_xor(v, 1); v += __shfl_xor(v, 2); \
    v += __shfl_xor(v, 4); v += __shfl_xor(v, 8); \
    if (cc == 0) sc_s[wc * NN + (wr * 4 + jj) * 16 + q * 4 + r] = v; }

  REDW(p00, 0, 0) REDW(p01, 0, 1) REDW(p02, 0, 2) REDW(p03, 0, 3)
  REDW(p10, 1, 0) REDW(p11, 1, 1) REDW(p12, 1, 2) REDW(p13, 1, 3)
  REDW(p20, 2, 0) REDW(p21, 2, 1) REDW(p22, 2, 2) REDW(p23, 2, 3)
  REDW(p30, 3, 0) REDW(p31, 3, 1) REDW(p32, 3, 2) REDW(p33, 3, 3)
  __syncthreads();

  // ---- softmax over j (first 256 threads active; all hit barriers) ----
  float score = 0.f, e = 0.f;
  if (t < NN) {
    score = sc_s[t] + sc_s[NN + t] + sc_s[2 * NN + t] + sc_s[3 * NN + t] + b2[0];
    if (t == i) score = -1.0e9f;
    red_s[t] = score;
  }
  __syncthreads();
  for (int s = 128; s > 0; s >>= 1) {
    if (t < s) red_s[t] = fmaxf(red_s[t], red_s[t + s]);
    __syncthreads();
  }
  const float m = red_s[0];
  __syncthreads();
  if (t < NN) { e = __expf(score - m); red_s[t] = e; }
  __syncthreads();
  for (int s = 128; s > 0; s >>= 1) {
    if (t < s) red_s[t] += red_s[t + s];
    __syncthreads();
  }
  if (t < NN) out[(size_t)bi * NN + t] = e / red_s[0];
}

extern "C" void kernel_launch(void* const* d_in, const int* in_sizes, int n_in,
                              void* d_out, int out_size, void* d_ws, size_t ws_size,
                              hipStream_t stream) {
  const float* X  = (const float*)d_in[0];
  const float* W1 = (const float*)d_in[1];
  const float* b1 = (const float*)d_in[2];
  const float* W2 = (const float*)d_in[3];
  const float* b2 = (const float*)d_in[4];
  float* out = (float*)d_out;

  float*     Sws  = (float*)d_ws;                                 // 1 MB
  float*     Tws  = Sws + (size_t)BB * NN * HH;                   // 1 MB
  _Float16*  Wf16 = (_Float16*)(Tws + (size_t)BB * NN * HH);      // 256 KB

  prep_kernel<<<256, 256, 0, stream>>>(X, W1, Sws, Tws, Wf16);
  score_mfma<<<BB * NN, 1024, 0, stream>>>(X, b1, W2, b2, Sws, Tws, Wf16, out);
}

// Round 8
// 271.766 us; speedup vs baseline: 1.3828x; 1.3828x over previous
//
#include <hip/hip_runtime.h>

#define BB 4
#define NN 256
#define DD 256
#define HH 256
#define NEGV -1.0e9f

typedef _Float16 half8 __attribute__((ext_vector_type(8)));
typedef __fp16   fp16x2 __attribute__((ext_vector_type(2)));
typedef float floatx4 __attribute__((ext_vector_type(4)));

// ---------------- prep: Wc/Wd -> f16 kstep-major; Xt = X^T; S/T projections ----
// Wst layout: [ks 0..15][h 0..255][kloc 0..31] halves; global k = ks*32+kloc,
// k = 2*d + t (t=0: Wc[d][h] diff-weight, t=1: Wd[d][h] prod-weight).
// Xt layout: [b][d][j] fp32 (so score staging reads are j-contiguous).
__global__ __launch_bounds__(256) void prep_kernel(const float* __restrict__ X,
                                                   const float* __restrict__ W1,
                                                   float* __restrict__ S,
                                                   float* __restrict__ T,
                                                   _Float16* __restrict__ Wst,
                                                   float* __restrict__ Xt) {
  const int g = blockIdx.x;    // 0..255
  const int h = threadIdx.x;   // 0..255

  // (a) weight conversion for d = g  ->  ks = g>>4, kloc = 2*(g&15)+{0,1}
  {
    const float wcv = W1[(size_t)(2 * DD + g) * HH + h];
    const float wdv = W1[(size_t)(3 * DD + g) * HH + h];
    _Float16* p = Wst + ((size_t)(g >> 4) * HH * 32 + (size_t)h * 32 + 2 * (g & 15));
    p[0] = (_Float16)wcv;
    p[1] = (_Float16)wdv;
  }

  // (b) S/T for 4 rows + X transpose
  const int row0 = g * 4;
  __shared__ float xr[4][DD];
#pragma unroll
  for (int r = 0; r < 4; ++r) xr[r][h] = X[(size_t)(row0 + r) * DD + h];
  __syncthreads();

  // transpose: Xt[b][d=h][j=row]   (b = row0>>8 constant within block)
  {
    const int bb = row0 >> 8;
    const int j0 = row0 & 255;
    float* xt = Xt + (size_t)bb * DD * NN + (size_t)h * NN + j0;
    xt[0] = xr[0][h]; xt[1] = xr[1][h]; xt[2] = xr[2][h]; xt[3] = xr[3][h];
  }

  const float* __restrict__ Wa = W1;
  const float* __restrict__ Wb = W1 + (size_t)DD * HH;
  float sa0 = 0.f, sa1 = 0.f, sa2 = 0.f, sa3 = 0.f;
  float sb0 = 0.f, sb1 = 0.f, sb2 = 0.f, sb3 = 0.f;
  for (int d = 0; d < DD; ++d) {
    const float wa = Wa[(size_t)d * HH + h];
    const float wb = Wb[(size_t)d * HH + h];
    sa0 = fmaf(xr[0][d], wa, sa0);  sb0 = fmaf(xr[0][d], wb, sb0);
    sa1 = fmaf(xr[1][d], wa, sa1);  sb1 = fmaf(xr[1][d], wb, sb1);
    sa2 = fmaf(xr[2][d], wa, sa2);  sb2 = fmaf(xr[2][d], wb, sb2);
    sa3 = fmaf(xr[3][d], wa, sa3);  sb3 = fmaf(xr[3][d], wb, sb3);
  }
  S[(size_t)(row0 + 0) * HH + h] = sa0;  T[(size_t)(row0 + 0) * HH + h] = sb0;
  S[(size_t)(row0 + 1) * HH + h] = sa1;  T[(size_t)(row0 + 1) * HH + h] = sb1;
  S[(size_t)(row0 + 2) * HH + h] = sa2;  T[(size_t)(row0 + 2) * HH + h] = sb2;
  S[(size_t)(row0 + 3) * HH + h] = sa3;  T[(size_t)(row0 + 3) * HH + h] = sb3;
}

// A-fragment pack, no stack objects.
__device__ __forceinline__ half8 make_afrag(float ia, float ib, float ic, float id,
                                            float ja, float jb, float jc, float jd) {
  fp16x2 p0 = __builtin_amdgcn_cvt_pkrtz(__builtin_fabsf(ia - ja), ia * ja);
  fp16x2 p1 = __builtin_amdgcn_cvt_pkrtz(__builtin_fabsf(ib - jb), ib * jb);
  fp16x2 p2 = __builtin_amdgcn_cvt_pkrtz(__builtin_fabsf(ic - jc), ic * jc);
  fp16x2 p3 = __builtin_amdgcn_cvt_pkrtz(__builtin_fabsf(id - jd), id * jd);
  uint4 u;
  u.x = __builtin_bit_cast(unsigned int, p0);
  u.y = __builtin_bit_cast(unsigned int, p1);
  u.z = __builtin_bit_cast(unsigned int, p2);
  u.w = __builtin_bit_cast(unsigned int, p3);
  return __builtin_bit_cast(half8, u);
}

#define MFMA16(af, bf, acc) acc = __builtin_amdgcn_mfma_f32_16x16x32_f16(af, bf, acc, 0, 0, 0)

// ---------------- score: raw scores for one (b,i) x 64-j slice -----------------
// 4096 blocks = (b*256+i)*4 + jblk; 512 threads = 8 waves (wj = wid&1 j-group,
// hg = wid>>1 h-group). Wave: 2 j-tiles x 4 h-tiles -> 8 named floatx4 acc (32 VGPR).
// A and B staged in LDS per kstep (double-buffered, coalesced global loads).
// LDS ~62 KB -> 2 blocks/CU -> 4 waves/EU -> 128-VGPR allocator target (R3-proven).
__global__ __launch_bounds__(512) void score_mfma(
    const float* __restrict__ X,  const float* __restrict__ b1,
    const float* __restrict__ W2, const float* __restrict__ b2,
    const float* __restrict__ S,  const float* __restrict__ T,
    const _Float16* __restrict__ Wst, const float* __restrict__ Xt,
    float* __restrict__ Sc) {

  const int blk   = blockIdx.x;
  const int bi    = blk >> 2;       // b*256 + i
  const int jblk  = blk & 3;
  const int jbase = jblk * 64;
  const int b     = bi >> 8;
  const int i     = bi & 255;
  const int t     = threadIdx.x;
  const int lane  = t & 63;
  const int wid   = t >> 6;         // 0..7
  const int wj    = wid & 1;        // j-group
  const int hg    = wid >> 1;       // h-group 0..3
  const int q     = lane >> 4;
  const int cc    = lane & 15;

  __shared__ __align__(16) float    xi_s[DD];
  __shared__ float pre_s[HH];
  __shared__ float w2_s[HH];
  __shared__ __align__(16) float    Xs[2][16 * 132];   // [kslice d][j 0..63 +pad]
  __shared__ __align__(16) _Float16 Bs[2][256 * 40];   // [h][kloc 0..31 +pad]
  __shared__ float sc_s[4][64];

  if (t < 256) {
    xi_s[t]  = X[(size_t)bi * DD + t];
    pre_s[t] = S[(size_t)bi * HH + t] + b1[t];
    w2_s[t]  = W2[t];
  }

  const float* __restrict__ Tb = T + (size_t)b * NN * HH;

  // staging roles
  const int hB = t >> 1, pB = t & 1;                 // B: 16 halves (32 B) each
  const char* __restrict__ WstB = (const char*)Wst;  // kstep ks at byte ks*16384
  const int bdst = hB * 80 + pB * 32;                // byte offset in Bs buf
  const int dX = t >> 5, jX = (t & 31) * 2;          // X: float2 each
  const float* __restrict__ xsrc = Xt + (size_t)b * DD * NN + jbase + jX;
  const int xdst = dX * 132 + jX;

  // fragment read offsets
  const int bro = (hg * 64 + cc) * 40 + q * 8;       // halves; hh advances +16*40
  const int jl0 = (wj * 2) * 16 + cc;                // j-local for jj=0; jj=1: +16
  const int xq  = q * 4 * 132;                       // row q*4 in Xs

  floatx4 a00 = (floatx4)0.f, a01 = (floatx4)0.f, a02 = (floatx4)0.f, a03 = (floatx4)0.f;
  floatx4 a10 = (floatx4)0.f, a11 = (floatx4)0.f, a12 = (floatx4)0.f, a13 = (floatx4)0.f;

  // prologue: stage kstep 0 into buffer 0
  {
    uint4 bv0 = *(const uint4*)(WstB + (size_t)t * 32);
    uint4 bv1 = *(const uint4*)(WstB + (size_t)t * 32 + 16);
    float2 xv = *(const float2*)(xsrc + (size_t)dX * NN);
    *(uint4*)((char*)&Bs[0][0] + bdst)      = bv0;
    *(uint4*)((char*)&Bs[0][0] + bdst + 16) = bv1;
    *(float2*)&Xs[0][xdst] = xv;
  }
  __syncthreads();

  for (int ks = 0; ks < 16; ++ks) {
    const int cur = ks & 1;
    uint4 nb0, nb1; float2 nx;
    if (ks < 15) {
      nb0 = *(const uint4*)(WstB + (size_t)(ks + 1) * 16384 + (size_t)t * 32);
      nb1 = *(const uint4*)(WstB + (size_t)(ks + 1) * 16384 + (size_t)t * 32 + 16);
      nx  = *(const float2*)(xsrc + (size_t)((ks + 1) * 16 + dX) * NN);
    }

    // ---- compute kstep ks from buffer cur ----
    {
      const float4 xiv = *(const float4*)&xi_s[ks * 16 + q * 4];
      const _Float16* __restrict__ bp = &Bs[cur][0];
      const float*    __restrict__ xp = &Xs[cur][0];
      const half8 bf0 = *(const half8*)&bp[bro];
      const half8 bf1 = *(const half8*)&bp[bro + 16 * 40];
      const half8 bf2 = *(const half8*)&bp[bro + 32 * 40];
      const half8 bf3 = *(const half8*)&bp[bro + 48 * 40];
      {
        const float x0 = xp[xq + jl0];
        const float x1 = xp[xq + 132 + jl0];
        const float x2 = xp[xq + 264 + jl0];
        const float x3 = xp[xq + 396 + jl0];
        const half8 af = make_afrag(xiv.x, xiv.y, xiv.z, xiv.w, x0, x1, x2, x3);
        MFMA16(af, bf0, a00); MFMA16(af, bf1, a01);
        MFMA16(af, bf2, a02); MFMA16(af, bf3, a03);
      }
      {
        const float x0 = xp[xq + jl0 + 16];
        const float x1 = xp[xq + 132 + jl0 + 16];
        const float x2 = xp[xq + 264 + jl0 + 16];
        const float x3 = xp[xq + 396 + jl0 + 16];
        const half8 af = make_afrag(xiv.x, xiv.y, xiv.z, xiv.w, x0, x1, x2, x3);
        MFMA16(af, bf0, a10); MFMA16(af, bf1, a11);
        MFMA16(af, bf2, a12); MFMA16(af, bf3, a13);
      }
    }

    if (ks < 15) {
      const int nxt = cur ^ 1;
      *(uint4*)((char*)&Bs[nxt][0] + bdst)      = nb0;
      *(uint4*)((char*)&Bs[nxt][0] + bdst + 16) = nb1;
      *(float2*)&Xs[nxt][xdst] = nx;
    }
    __syncthreads();
  }

  // ---- epilogue: + S_i + T_j + b1, silu, dot w2 ----
  float p00 = 0.f, p01 = 0.f, p02 = 0.f, p03 = 0.f;
  float p10 = 0.f, p11 = 0.f, p12 = 0.f, p13 = 0.f;

#define EPI_ONE(A, jj, r, P) { \
    const float tv = Tb[(size_t)(jbase + (wj * 2 + jj) * 16 + q * 4 + r) * HH + h]; \
    const float hv = A[r] + pv + tv; \
    const float sv = hv * __frcp_rn(1.f + __expf(-hv)); \
    P = fmaf(sv, w2v, P); }

#define EPI_HH(hh, A0, A1) { \
    const int h = hg * 64 + hh * 16 + cc; \
    const float w2v = w2_s[h]; \
    const float pv  = pre_s[h]; \
    EPI_ONE(A0, 0, 0, p00) EPI_ONE(A0, 0, 1, p01) EPI_ONE(A0, 0, 2, p02) EPI_ONE(A0, 0, 3, p03) \
    EPI_ONE(A1, 1, 0, p10) EPI_ONE(A1, 1, 1, p11) EPI_ONE(A1, 1, 2, p12) EPI_ONE(A1, 1, 3, p13) }

  EPI_HH(0, a00, a10)
  EPI_HH(1, a01, a11)
  EPI_HH(2, a02, a12)
  EPI_HH(3, a03, a13)

#define REDW(P, jj, r) { \
    float v = P; \
    v += __shfl_xor(v, 1); v += __shfl_xor(v, 2); \
    v += __shfl_xor(v, 4); v += __shfl_xor(v, 8); \
    if (cc == 0) sc_s[hg][(wj * 2 + jj) * 16 + q * 4 + r] = v; }

  REDW(p00, 0, 0) REDW(p01, 0, 1) REDW(p02, 0, 2) REDW(p03, 0, 3)
  REDW(p10, 1, 0) REDW(p11, 1, 1) REDW(p12, 1, 2) REDW(p13, 1, 3)
  __syncthreads();

  if (t < 64) {
    float s = sc_s[0][t] + sc_s[1][t] + sc_s[2][t] + sc_s[3][t] + b2[0];
    const int jg = jbase + t;
    if (jg == i) s = NEGV;
    Sc[(size_t)bi * NN + jg] = s;
  }
}

// ---------------- softmax over j, one block per (b,i) --------------------------
__global__ __launch_bounds__(256) void softmax_kernel(const float* __restrict__ Sc,
                                                      float* __restrict__ out) {
  const int bi = blockIdx.x;
  const int t  = threadIdx.x;
  __shared__ float red[NN];
  const float s = Sc[(size_t)bi * NN + t];
  red[t] = s;
  __syncthreads();
  for (int k = 128; k > 0; k >>= 1) {
    if (t < k) red[t] = fmaxf(red[t], red[t + k]);
    __syncthreads();
  }
  const float m = red[0];
  __syncthreads();
  const float e = __expf(s - m);
  red[t] = e;
  __syncthreads();
  for (int k = 128; k > 0; k >>= 1) {
    if (t < k) red[t] += red[t + k];
    __syncthreads();
  }
  out[(size_t)bi * NN + t] = e / red[0];
}

extern "C" void kernel_launch(void* const* d_in, const int* in_sizes, int n_in,
                              void* d_out, int out_size, void* d_ws, size_t ws_size,
                              hipStream_t stream) {
  const float* X  = (const float*)d_in[0];
  const float* W1 = (const float*)d_in[1];
  const float* b1 = (const float*)d_in[2];
  const float* W2 = (const float*)d_in[3];
  const float* b2 = (const float*)d_in[4];
  float* out = (float*)d_out;

  float*     Sws = (float*)d_ws;                         // 1 MB
  float*     Tws = Sws + (size_t)BB * NN * HH;           // 1 MB
  _Float16*  Wst = (_Float16*)(Tws + (size_t)BB * NN * HH);  // 256 KB (16*256*32 halves)
  float*     Xtw = (float*)(Wst + (size_t)16 * HH * 32); // 1 MB
  float*     Scw = Xtw + (size_t)BB * DD * NN;           // 1 MB

  prep_kernel<<<256, 256, 0, stream>>>(X, W1, Sws, Tws, Wst, Xtw);
  score_mfma<<<BB * NN * 4, 512, 0, stream>>>(X, b1, W2, b2, Sws, Tws, Wst, Xtw, Scw);
  softmax_kernel<<<BB * NN, 256, 0, stream>>>(Scw, out);
}

// Round 9
// 219.728 us; speedup vs baseline: 1.7103x; 1.2368x over previous
//
#include <hip/hip_runtime.h>

#define BB 4
#define NN 256
#define DD 256
#define HH 256
#define NEGV -1.0e9f

typedef _Float16 half8 __attribute__((ext_vector_type(8)));
typedef __fp16   fp16x2 __attribute__((ext_vector_type(2)));
typedef float floatx4 __attribute__((ext_vector_type(4)));

// ---------------- prep: Wc/Wd -> f16 fragment-contiguous; Xt = X^T; S/T -------
// Wst layout: [ks 0..15][hgrp 0..15][q 0..3][cc 0..15][e 0..7] halves.
// Fragment (ks,hgrp,q) holds B16[k=ks*32+q*8+e][h=hgrp*16+cc]; k=2*d+t
// (t=0: Wc[d][h], t=1: Wd[d][h]).  A wave's read is base + lane*16B: conflict-free.
// Xt layout: [b][d][j] fp32 (score staging reads j-contiguous).
__global__ __launch_bounds__(256) void prep_kernel(const float* __restrict__ X,
                                                   const float* __restrict__ W1,
                                                   float* __restrict__ S,
                                                   float* __restrict__ T,
                                                   _Float16* __restrict__ Wst,
                                                   float* __restrict__ Xt) {
  const int g = blockIdx.x;    // d = 0..255
  const int h = threadIdx.x;   // 0..255

  // (a) weight conversion for d = g
  {
    const float wcv = W1[(size_t)(2 * DD + g) * HH + h];
    const float wdv = W1[(size_t)(3 * DD + g) * HH + h];
    const int ks = g >> 4;
    const int dd = g & 15;
    const int q  = dd >> 2;            // kloc = 2*dd + t; q = kloc>>3
    const int e  = (dd & 3) * 2;       // e = kloc&7
    const int hgrp = h >> 4;
    const int ccw  = h & 15;
    _Float16* p = Wst + ((size_t)((ks * 16 + hgrp) * 4 + q) * 16 + ccw) * 8 + e;
    p[0] = (_Float16)wcv;
    p[1] = (_Float16)wdv;
  }

  // (b) S/T for 4 rows + X transpose
  const int row0 = g * 4;
  __shared__ float xr[4][DD];
#pragma unroll
  for (int r = 0; r < 4; ++r) xr[r][h] = X[(size_t)(row0 + r) * DD + h];
  __syncthreads();

  {
    const int bb = row0 >> 8;
    const int j0 = row0 & 255;
    float* xt = Xt + (size_t)bb * DD * NN + (size_t)h * NN + j0;
    xt[0] = xr[0][h]; xt[1] = xr[1][h]; xt[2] = xr[2][h]; xt[3] = xr[3][h];
  }

  const float* __restrict__ Wa = W1;
  const float* __restrict__ Wb = W1 + (size_t)DD * HH;
  float sa0 = 0.f, sa1 = 0.f, sa2 = 0.f, sa3 = 0.f;
  float sb0 = 0.f, sb1 = 0.f, sb2 = 0.f, sb3 = 0.f;
  for (int d = 0; d < DD; ++d) {
    const float wa = Wa[(size_t)d * HH + h];
    const float wb = Wb[(size_t)d * HH + h];
    sa0 = fmaf(xr[0][d], wa, sa0);  sb0 = fmaf(xr[0][d], wb, sb0);
    sa1 = fmaf(xr[1][d], wa, sa1);  sb1 = fmaf(xr[1][d], wb, sb1);
    sa2 = fmaf(xr[2][d], wa, sa2);  sb2 = fmaf(xr[2][d], wb, sb2);
    sa3 = fmaf(xr[3][d], wa, sa3);  sb3 = fmaf(xr[3][d], wb, sb3);
  }
  S[(size_t)(row0 + 0) * HH + h] = sa0;  T[(size_t)(row0 + 0) * HH + h] = sb0;
  S[(size_t)(row0 + 1) * HH + h] = sa1;  T[(size_t)(row0 + 1) * HH + h] = sb1;
  S[(size_t)(row0 + 2) * HH + h] = sa2;  T[(size_t)(row0 + 2) * HH + h] = sb2;
  S[(size_t)(row0 + 3) * HH + h] = sa3;  T[(size_t)(row0 + 3) * HH + h] = sb3;
}

// A-fragment pack, no stack objects (abs folds into cvt_pkrtz src modifier).
__device__ __forceinline__ half8 make_afrag(float ia, float ib, float ic, float id,
                                            float ja, float jb, float jc, float jd) {
  fp16x2 p0 = __builtin_amdgcn_cvt_pkrtz(__builtin_fabsf(ia - ja), ia * ja);
  fp16x2 p1 = __builtin_amdgcn_cvt_pkrtz(__builtin_fabsf(ib - jb), ib * jb);
  fp16x2 p2 = __builtin_amdgcn_cvt_pkrtz(__builtin_fabsf(ic - jc), ic * jc);
  fp16x2 p3 = __builtin_amdgcn_cvt_pkrtz(__builtin_fabsf(id - jd), id * jd);
  uint4 u;
  u.x = __builtin_bit_cast(unsigned int, p0);
  u.y = __builtin_bit_cast(unsigned int, p1);
  u.z = __builtin_bit_cast(unsigned int, p2);
  u.w = __builtin_bit_cast(unsigned int, p3);
  return __builtin_bit_cast(half8, u);
}

#define MFMA16(af, bf, acc) acc = __builtin_amdgcn_mfma_f32_16x16x32_f16(af, bf, acc, 0, 0, 0)

// ---------------- score: one block per (b,i) x 128-j half ----------------------
// 2048 blocks x 512 thr = 8 waves: wj = wid&1 (j-group of 64), hg = wid>>1 (h-group
// of 64). Wave tile: 4 j-tiles x 4 h-tiles = 16 MFMA / (4 B-b128 + 16 X-b32) per
// kstep (2x the MFMA:LDS ratio of R8). B-frag reads are lane-contiguous (bank-
// conflict-free); Xs [d][j] stride-132 b32 reads verified conflict-free.
__global__ __launch_bounds__(512) void score_mfma(
    const float* __restrict__ X,  const float* __restrict__ b1,
    const float* __restrict__ W2, const float* __restrict__ b2,
    const float* __restrict__ S,  const float* __restrict__ T,
    const _Float16* __restrict__ Wst, const float* __restrict__ Xt,
    float* __restrict__ Sc) {

  const int blk   = blockIdx.x;
  const int bi    = blk >> 1;       // b*256 + i
  const int jhalf = blk & 1;
  const int jbase = jhalf * 128;
  const int b     = bi >> 8;
  const int i     = bi & 255;
  const int t     = threadIdx.x;
  const int lane  = t & 63;
  const int wid   = t >> 6;         // 0..7
  const int wj    = wid & 1;
  const int hg    = wid >> 1;       // 0..3
  const int q     = lane >> 4;
  const int cc    = lane & 15;

  __shared__ __align__(16) float    xi_s[DD];
  __shared__ float pre_s[HH];
  __shared__ float w2_s[HH];
  __shared__ __align__(16) float    Xs[2][16 * 132];   // [d 0..15][j 0..127 +pad]
  __shared__ __align__(16) _Float16 Bs[2][8192];       // fragment-contiguous 16 KB
  __shared__ float sc_s[4][128];

  if (t < 256) {
    xi_s[t]  = X[(size_t)bi * DD + t];
    pre_s[t] = S[(size_t)bi * HH + t] + b1[t];
    w2_s[t]  = W2[t];
  }

  const float* __restrict__ Tb = T + (size_t)b * NN * HH;

  // staging roles: B thread t -> 32 B at byte t*32 (contiguous); X -> float4
  const char* __restrict__ WstB = (const char*)Wst;   // kstep ks at byte ks*16384
  const int dX = t >> 5;                 // 0..15
  const int jX = (t & 31) * 4;           // 0..124
  const float* __restrict__ xsrc = Xt + (size_t)b * DD * NN + jbase + jX;
  const int xdst = dX * 132 + jX;

  // fragment read offsets
  const int bro = hg * 2048 + lane * 8;  // halves; hh advances +512
  const int jl  = wj * 64 + cc;          // j-local for jj=0; jj advances +16
  const int xq  = q * 528;               // row q*4 in Xs (132*4)

  floatx4 a00 = (floatx4)0.f, a01 = (floatx4)0.f, a02 = (floatx4)0.f, a03 = (floatx4)0.f;
  floatx4 a10 = (floatx4)0.f, a11 = (floatx4)0.f, a12 = (floatx4)0.f, a13 = (floatx4)0.f;
  floatx4 a20 = (floatx4)0.f, a21 = (floatx4)0.f, a22 = (floatx4)0.f, a23 = (floatx4)0.f;
  floatx4 a30 = (floatx4)0.f, a31 = (floatx4)0.f, a32 = (floatx4)0.f, a33 = (floatx4)0.f;

  // prologue: stage kstep 0 into buffer 0
  {
    uint4 bv0 = *(const uint4*)(WstB + (size_t)t * 32);
    uint4 bv1 = *(const uint4*)(WstB + (size_t)t * 32 + 16);
    float4 xv = *(const float4*)(xsrc + (size_t)dX * NN);
    *(uint4*)((char*)&Bs[0][0] + t * 32)      = bv0;
    *(uint4*)((char*)&Bs[0][0] + t * 32 + 16) = bv1;
    *(float4*)&Xs[0][xdst] = xv;
  }
  __syncthreads();

  for (int ks = 0; ks < 16; ++ks) {
    const int cur = ks & 1;
    uint4 nb0, nb1; float4 nx;
    if (ks < 15) {
      nb0 = *(const uint4*)(WstB + (size_t)(ks + 1) * 16384 + (size_t)t * 32);
      nb1 = *(const uint4*)(WstB + (size_t)(ks + 1) * 16384 + (size_t)t * 32 + 16);
      nx  = *(const float4*)(xsrc + (size_t)((ks + 1) * 16 + dX) * NN);
    }

    // ---- compute kstep ks from buffer cur ----
    {
      const float4 xiv = *(const float4*)&xi_s[ks * 16 + q * 4];
      const _Float16* __restrict__ bp = &Bs[cur][0];
      const float*    __restrict__ xp = &Xs[cur][0];
      const half8 bf0 = *(const half8*)&bp[bro];
      const half8 bf1 = *(const half8*)&bp[bro + 512];
      const half8 bf2 = *(const half8*)&bp[bro + 1024];
      const half8 bf3 = *(const half8*)&bp[bro + 1536];
      {
        const float x0 = xp[xq + jl];
        const float x1 = xp[xq + 132 + jl];
        const float x2 = xp[xq + 264 + jl];
        const float x3 = xp[xq + 396 + jl];
        const half8 af = make_afrag(xiv.x, xiv.y, xiv.z, xiv.w, x0, x1, x2, x3);
        MFMA16(af, bf0, a00); MFMA16(af, bf1, a01); MFMA16(af, bf2, a02); MFMA16(af, bf3, a03);
      }
      {
        const float x0 = xp[xq + jl + 16];
        const float x1 = xp[xq + 132 + jl + 16];
        const float x2 = xp[xq + 264 + jl + 16];
        const float x3 = xp[xq + 396 + jl + 16];
        const half8 af = make_afrag(xiv.x, xiv.y, xiv.z, xiv.w, x0, x1, x2, x3);
        MFMA16(af, bf0, a10); MFMA16(af, bf1, a11); MFMA16(af, bf2, a12); MFMA16(af, bf3, a13);
      }
      {
        const float x0 = xp[xq + jl + 32];
        const float x1 = xp[xq + 132 + jl + 32];
        const float x2 = xp[xq + 264 + jl + 32];
        const float x3 = xp[xq + 396 + jl + 32];
        const half8 af = make_afrag(xiv.x, xiv.y, xiv.z, xiv.w, x0, x1, x2, x3);
        MFMA16(af, bf0, a20); MFMA16(af, bf1, a21); MFMA16(af, bf2, a22); MFMA16(af, bf3, a23);
      }
      {
        const float x0 = xp[xq + jl + 48];
        const float x1 = xp[xq + 132 + jl + 48];
        const float x2 = xp[xq + 264 + jl + 48];
        const float x3 = xp[xq + 396 + jl + 48];
        const half8 af = make_afrag(xiv.x, xiv.y, xiv.z, xiv.w, x0, x1, x2, x3);
        MFMA16(af, bf0, a30); MFMA16(af, bf1, a31); MFMA16(af, bf2, a32); MFMA16(af, bf3, a33);
      }
    }

    if (ks < 15) {
      const int nxt = cur ^ 1;
      *(uint4*)((char*)&Bs[nxt][0] + t * 32)      = nb0;
      *(uint4*)((char*)&Bs[nxt][0] + t * 32 + 16) = nb1;
      *(float4*)&Xs[nxt][xdst] = nx;
    }
    __syncthreads();
  }

  // ---- epilogue: + S_i + T_j + b1, silu, dot w2 ----
  float p00 = 0.f, p01 = 0.f, p02 = 0.f, p03 = 0.f;
  float p10 = 0.f, p11 = 0.f, p12 = 0.f, p13 = 0.f;
  float p20 = 0.f, p21 = 0.f, p22 = 0.f, p23 = 0.f;
  float p30 = 0.f, p31 = 0.f, p32 = 0.f, p33 = 0.f;

#define EPI_ONE(A, jj, r, P) { \
    const float tv = Tb[(size_t)(jbase + wj * 64 + jj * 16 + q * 4 + r) * HH + h]; \
    const float hv = A[r] + pv + tv; \
    const float sv = hv * __frcp_rn(1.f + __expf(-hv)); \
    P = fmaf(sv, w2v, P); }

#define EPI_HH(hh, A0, A1, A2, A3) { \
    const int h = hg * 64 + hh * 16 + cc; \
    const float w2v = w2_s[h]; \
    const float pv  = pre_s[h]; \
    EPI_ONE(A0, 0, 0, p00) EPI_ONE(A0, 0, 1, p01) EPI_ONE(A0, 0, 2, p02) EPI_ONE(A0, 0, 3, p03) \
    EPI_ONE(A1, 1, 0, p10) EPI_ONE(A1, 1, 1, p11) EPI_ONE(A1, 1, 2, p12) EPI_ONE(A1, 1, 3, p13) \
    EPI_ONE(A2, 2, 0, p20) EPI_ONE(A2, 2, 1, p21) EPI_ONE(A2, 2, 2, p22) EPI_ONE(A2, 2, 3, p23) \
    EPI_ONE(A3, 3, 0, p30) EPI_ONE(A3, 3, 1, p31) EPI_ONE(A3, 3, 2, p32) EPI_ONE(A3, 3, 3, p33) }

  EPI_HH(0, a00, a10, a20, a30)
  EPI_HH(1, a01, a11, a21, a31)
  EPI_HH(2, a02, a12, a22, a32)
  EPI_HH(3, a03, a13, a23, a33)

#define REDW(P, jj, r) { \
    float v = P; \
    v += __shfl_xor(v, 1); v += __shfl_xor(v, 2); \
    v += __shfl_xor(v, 4); v += __shfl_xor(v, 8); \
    if (cc == 0) sc_s[hg][wj * 64 + jj * 16 + q * 4 + r] = v; }

  REDW(p00, 0, 0) REDW(p01, 0, 1) REDW(p02, 0, 2) REDW(p03, 0, 3)
  REDW(p10, 1, 0) REDW(p11, 1, 1) REDW(p12, 1, 2) REDW(p13, 1, 3)
  REDW(p20, 2, 0) REDW(p21, 2, 1) REDW(p22, 2, 2) REDW(p23, 2, 3)
  REDW(p30, 3, 0) REDW(p31, 3, 1) REDW(p32, 3, 2) REDW(p33, 3, 3)
  __syncthreads();

  if (t < 128) {
    float s = sc_s[0][t] + sc_s[1][t] + sc_s[2][t] + sc_s[3][t] + b2[0];
    const int jg = jbase + t;
    if (jg == i) s = NEGV;
    Sc[(size_t)bi * NN + jg] = s;
  }
}

// ---------------- softmax over j, one block per (b,i) --------------------------
__global__ __launch_bounds__(256) void softmax_kernel(const float* __restrict__ Sc,
                                                      float* __restrict__ out) {
  const int bi = blockIdx.x;
  const int t  = threadIdx.x;
  __shared__ float red[NN];
  const float s = Sc[(size_t)bi * NN + t];
  red[t] = s;
  __syncthreads();
  for (int k = 128; k > 0; k >>= 1) {
    if (t < k) red[t] = fmaxf(red[t], red[t + k]);
    __syncthreads();
  }
  const float m = red[0];
  __syncthreads();
  const float e = __expf(s - m);
  red[t] = e;
  __syncthreads();
  for (int k = 128; k > 0; k >>= 1) {
    if (t < k) red[t] += red[t + k];
    __syncthreads();
  }
  out[(size_t)bi * NN + t] = e / red[0];
}

extern "C" void kernel_launch(void* const* d_in, const int* in_sizes, int n_in,
                              void* d_out, int out_size, void* d_ws, size_t ws_size,
                              hipStream_t stream) {
  const float* X  = (const float*)d_in[0];
  const float* W1 = (const float*)d_in[1];
  const float* b1 = (const float*)d_in[2];
  const float* W2 = (const float*)d_in[3];
  const float* b2 = (const float*)d_in[4];
  float* out = (float*)d_out;

  float*     Sws = (float*)d_ws;                             // 1 MB
  float*     Tws = Sws + (size_t)BB * NN * HH;               // 1 MB
  _Float16*  Wst = (_Float16*)(Tws + (size_t)BB * NN * HH);  // 256 KB
  float*     Xtw = (float*)(Wst + (size_t)16 * HH * 32);     // 1 MB
  float*     Scw = Xtw + (size_t)BB * DD * NN;               // 1 MB

  prep_kernel<<<256, 256, 0, stream>>>(X, W1, Sws, Tws, Wst, Xtw);
  score_mfma<<<BB * NN * 2, 512, 0, stream>>>(X, b1, W2, b2, Sws, Tws, Wst, Xtw, Scw);
  softmax_kernel<<<BB * NN, 256, 0, stream>>>(Scw, out);
}